// Round 9
// baseline (762.288 us; speedup 1.0000x reference)
//
#include <hip/hip_runtime.h>
#include <math.h>

// Problem constants (GATModel: N=50000, E=800000, F_IN=128, HID=OUT=64, H=4)
constexpr int NNODE = 50000;
constexpr int FIN   = 128;
constexpr int HID   = 64;
constexpr int NH    = 4;
constexpr int NC    = 256;   // NH * HID
constexpr float NEG = 0.2f;
constexpr int MPAD  = 50048; // NNODE padded to 64-row tiles (782*64)

typedef unsigned short u16;
typedef short bf16x8 __attribute__((ext_vector_type(8)));
typedef float f32x4 __attribute__((ext_vector_type(4)));

__device__ __forceinline__ u16 f2bf(float f) {  // round-to-nearest-even
  unsigned int u = __float_as_uint(f);
  return (u16)((u + 0x7FFF + ((u >> 16) & 1)) >> 16);
}
__device__ __forceinline__ float bf2f(u16 h) {
  return __uint_as_float(((unsigned int)h) << 16);
}
__device__ __forceinline__ float readlane_f(float v, int l) {
  return __int_as_float(__builtin_amdgcn_readlane(__float_as_int(v), l));
}

// pack W[K][256] fp32 -> Bp bf16 in MFMA B-fragment order: Bp[(k>>3)*256 + n][k&7]
__global__ __launch_bounds__(256) void pack_W(const float* __restrict__ W, u16* __restrict__ Bp, int total) {
  int i = blockIdx.x * 256 + threadIdx.x;  // i = k*256 + n
  if (i >= total) return;
  int k = i >> 8, n = i & 255;
  Bp[((size_t)(k >> 3) * 256 + n) * 8 + (k & 7)] = f2bf(W[i]);
}

// ---------------- CSR build (by destination) ----------------
__global__ __launch_bounds__(256) void count_deg(const int* __restrict__ ei, int* __restrict__ deg, int E) {
  int i = blockIdx.x * 256 + threadIdx.x;
  if (i < E) atomicAdd(&deg[ei[E + i]], 1);
}

__global__ __launch_bounds__(256) void scan_phase1(const int* __restrict__ deg,
                                                   int* __restrict__ blockSums, int n) {
  __shared__ int sm[256];
  int tid = threadIdx.x;
  int i = blockIdx.x * 256 + tid;
  sm[tid] = (i < n) ? deg[i] : 0;
  __syncthreads();
#pragma unroll
  for (int o = 128; o > 0; o >>= 1) {
    if (tid < o) sm[tid] += sm[tid + o];
    __syncthreads();
  }
  if (tid == 0) blockSums[blockIdx.x] = sm[0];
}

__global__ __launch_bounds__(256) void scan_phase2(const int* __restrict__ blockSums,
                                                   int* __restrict__ blockOffs, int nb,
                                                   int* __restrict__ total_out) {
  __shared__ int sm[256];
  int tid = threadIdx.x;
  int v = (tid < nb) ? blockSums[tid] : 0;
  sm[tid] = v;
  __syncthreads();
#pragma unroll
  for (int o = 1; o < 256; o <<= 1) {
    int t = (tid >= o) ? sm[tid - o] : 0;
    __syncthreads();
    sm[tid] += t;
    __syncthreads();
  }
  if (tid < nb) blockOffs[tid] = sm[tid] - v;  // exclusive
  if (tid == 255) *total_out = sm[255];        // offs[N] = E
}

__global__ __launch_bounds__(256) void scan_phase3(const int* __restrict__ deg,
                                                   const int* __restrict__ blockOffs,
                                                   int* __restrict__ offs, int* __restrict__ cursor, int n) {
  __shared__ int sm[256];
  int tid = threadIdx.x;
  int i = blockIdx.x * 256 + tid;
  int v = (i < n) ? deg[i] : 0;
  sm[tid] = v;
  __syncthreads();
#pragma unroll
  for (int o = 1; o < 256; o <<= 1) {
    int t = (tid >= o) ? sm[tid - o] : 0;
    __syncthreads();
    sm[tid] += t;
    __syncthreads();
  }
  int ex = sm[tid] - v + blockOffs[blockIdx.x];
  if (i < n) { offs[i] = ex; cursor[i] = ex; }
}

__global__ __launch_bounds__(256) void scatter_edges(const int* __restrict__ ei, int* __restrict__ cursor,
                                                     int* __restrict__ csr_src, int E) {
  int i = blockIdx.x * 256 + threadIdx.x;
  if (i < E) {
    int dst = ei[E + i];
    int pos = atomicAdd(&cursor[dst], 1);
    csr_src[pos] = ei[i];
  }
}

// ---------------- MFMA bf16 GEMM + alpha + packed bf16 store ----------------
// C[M,256] = A[M,K] @ B[K,256]bf16 (B pre-packed in fragment order).
// A-frag: lane holds A[m = lane&15][k = (lane>>4)*8 + j]
// B-frag: lane holds B[k = (lane>>4)*8 + j][n = lane&15]  (packed Bp)
// D: col = lane&15, row = (lane>>4)*4 + reg   [m89/m91-verified layouts]
template <int KS, bool AF32>  // K = 32*KS
__global__ __launch_bounds__(256) void gemm_mfma(
    const void* __restrict__ Aptr, const u16* __restrict__ Bp,
    const float* __restrict__ a_s, const float* __restrict__ a_d,
    u16* __restrict__ hf16, float* __restrict__ al_s, float* __restrict__ al_d, int M) {
  const int K = 32 * KS;
  int lane = threadIdx.x & 63;
  int wv = threadIdx.x >> 6;
  int q = lane >> 4, r = lane & 15;
  int m0 = blockIdx.x * 64 + wv * 16;

  bf16x8 af[KS];
  if (AF32) {
    int ar = m0 + r; if (ar >= M) ar = M - 1;   // x has exactly M rows; clamp (stores guarded)
    const float* arow = (const float*)Aptr + (size_t)ar * K + q * 8;
#pragma unroll
    for (int ks = 0; ks < KS; ++ks) {
      float4 v0 = *(const float4*)(arow + ks * 32);
      float4 v1 = *(const float4*)(arow + ks * 32 + 4);
      bf16x8 t;
      t[0] = (short)f2bf(v0.x); t[1] = (short)f2bf(v0.y);
      t[2] = (short)f2bf(v0.z); t[3] = (short)f2bf(v0.w);
      t[4] = (short)f2bf(v1.x); t[5] = (short)f2bf(v1.y);
      t[6] = (short)f2bf(v1.z); t[7] = (short)f2bf(v1.w);
      af[ks] = t;
    }
  } else {
    const u16* arow = (const u16*)Aptr + (size_t)(m0 + r) * K + q * 8;  // padded buffer
#pragma unroll
    for (int ks = 0; ks < KS; ++ks) af[ks] = *(const bf16x8*)(arow + ks * 32);
  }

  int node_base = m0 + q * 4;
#pragma unroll
  for (int h = 0; h < NH; ++h) {
    f32x4 acc[4];
#pragma unroll
    for (int c4 = 0; c4 < 4; ++c4) {
      acc[c4] = (f32x4){0.f, 0.f, 0.f, 0.f};
      const u16* bp = Bp + ((size_t)q * 256 + (h * 4 + c4) * 16 + r) * 8;
#pragma unroll
      for (int ks = 0; ks < KS; ++ks) {
        bf16x8 bf = *(const bf16x8*)(bp + (size_t)ks * 4 * 256 * 8);
        acc[c4] = __builtin_amdgcn_mfma_f32_16x16x32_bf16(af[ks], bf, acc[c4], 0, 0, 0);
      }
    }
    // epilogue for this head: alpha partials + packed bf16 stores
    float ps[4] = {0.f, 0.f, 0.f, 0.f}, pd[4] = {0.f, 0.f, 0.f, 0.f};
#pragma unroll
    for (int c4 = 0; c4 < 4; ++c4) {
      float sa = a_s[h * HID + c4 * 16 + r];
      float da = a_d[h * HID + c4 * 16 + r];
#pragma unroll
      for (int reg = 0; reg < 4; ++reg) {
        float v = acc[c4][reg];
        ps[reg] += v * sa;
        pd[reg] += v * da;
        int node = node_base + reg;
        if (node < M) hf16[(size_t)node * NC + (c4 * 16 + r) * NH + h] = f2bf(v);
      }
    }
#pragma unroll
    for (int reg = 0; reg < 4; ++reg) {
#pragma unroll
      for (int o = 1; o < 16; o <<= 1) {
        ps[reg] += __shfl_xor(ps[reg], o);
        pd[reg] += __shfl_xor(pd[reg], o);
      }
      int node = node_base + reg;
      if (r == 0 && node < M) {
        al_s[node * NH + h] = ps[reg];
        al_d[node * NH + h] = pd[reg];
      }
    }
  }
}

// ---------------- aggregation: persistent waves, dynamic node batches ----------------
// Each wave claims batches of NB nodes via atomicAdd on a queue counter ->
// load self-balances (fixes R7's 52% effective occupancy) with no sorting.
// Per node: mask-padded chunks of 8, depth-1 pipeline on gathers, denom via
// shfl tree. No max-shift: logits bounded ~|e|<20 => exp(e)/sum identical to
// reference's shifted softmax.
constexpr int NB = 4;  // nodes per claimed batch

template <bool FINAL>
__global__ __launch_bounds__(256) void agg_kernel(const u16* __restrict__ hf16,
                                                  const float4* __restrict__ al_s4,
                                                  const float4* __restrict__ al_d4,
                                                  const int* __restrict__ offs, const int* __restrict__ csr_src,
                                                  int* __restrict__ ctr,
                                                  const float* __restrict__ bias, void* __restrict__ out_v, int n) {
  int lane = threadIdx.x & 63;
  int lj = lane & 7;           // edge slot within chunk (weight lanes)
  int hsel = (lane >> 3) & 3;  // head handled by this lane in the weight phase
  float bi = bias[lane];

  for (;;) {
    int b = 0;
    if (lane == 0) b = atomicAdd(ctr, 1);
    b = __shfl(b, 0);
    int nbase = b * NB;
    if (nbase >= n) return;
    int nend = min(nbase + NB, n);

    for (int node = nbase; node < nend; ++node) {
      float4 ad = al_d4[node];
      float adv = hsel == 0 ? ad.x : (hsel == 1 ? ad.y : (hsel == 2 ? ad.z : ad.w));
      float c0 = 0.f, c1 = 0.f, c2 = 0.f, c3 = 0.f;
      float dacc = 0.f;          // per-head denom partial on lanes 0,8,16,24
      int s = offs[node], e = offs[node + 1];
      int nch = (e - s + 7) >> 3;
      int i = s;

      int vidx = 0;
      float4 as = make_float4(0.f, 0.f, 0.f, 0.f);
      ushort4 hv[8];
      if (nch > 0) {
        int id0 = i + lj; if (id0 >= e) id0 = e - 1;  // clamp: masked by w=0 later
        vidx = csr_src[id0];
        as = al_s4[vidx];
#pragma unroll
        for (int j = 0; j < 8; ++j) {
          int sa = __builtin_amdgcn_readlane(vidx, j);
          hv[j] = ((const ushort4*)(hf16 + (size_t)sa * NC))[lane];
        }
      }

      for (int ch = 0; ch < nch; ++ch) {
        bool last = (ch + 1 == nch);
        // ---- weight phase (lanes 0..31 meaningful) ----
        float asv = hsel == 0 ? as.x : (hsel == 1 ? as.y : (hsel == 2 ? as.z : as.w));
        float ev = asv + adv;
        ev = ev >= 0.f ? ev : NEG * ev;
        float wv = __expf(ev);
        if (i + lj >= e) wv = 0.f;                   // mask padded slots
        float t = wv;
        t += __shfl_xor(t, 1); t += __shfl_xor(t, 2); t += __shfl_xor(t, 4);
        dacc += t;                                   // lanes 0,8,16,24 hold head sums
        // ---- prefetch next chunk ----
        int vidx_n = 0;
        float4 as_n = make_float4(0.f, 0.f, 0.f, 0.f);
        ushort4 hn[8];
        if (!last) {
          int id1 = i + 8 + lj; if (id1 >= e) id1 = e - 1;
          vidx_n = csr_src[id1];
          as_n = al_s4[vidx_n];
#pragma unroll
          for (int j = 0; j < 8; ++j) {
            int sa = __builtin_amdgcn_readlane(vidx_n, j);
            hn[j] = ((const ushort4*)(hf16 + (size_t)sa * NC))[lane];
          }
        }
        // ---- accumulate current chunk ----
#pragma unroll
        for (int j = 0; j < 8; ++j) {
          float wx = readlane_f(wv, j);
          float wy = readlane_f(wv, 8 + j);
          float wz = readlane_f(wv, 16 + j);
          float ww = readlane_f(wv, 24 + j);
          c0 += wx * bf2f(hv[j].x);
          c1 += wy * bf2f(hv[j].y);
          c2 += wz * bf2f(hv[j].z);
          c3 += ww * bf2f(hv[j].w);
        }
        if (!last) {
          vidx = vidx_n; as = as_n;
#pragma unroll
          for (int j = 0; j < 8; ++j) hv[j] = hn[j];
        }
        i += 8;
      }
      float d0 = readlane_f(dacc, 0), d1 = readlane_f(dacc, 8);
      float d2 = readlane_f(dacc, 16), d3 = readlane_f(dacc, 24);
      float val = 0.25f * (c0 / (d0 + 1e-16f) + c1 / (d1 + 1e-16f) +
                           c2 / (d2 + 1e-16f) + c3 / (d3 + 1e-16f)) + bi;
      if (!FINAL) {
        // layer-1 output: relu + bf16 (feeds layer-2 MFMA GEMM directly)
        ((u16*)out_v)[(size_t)node * HID + lane] = f2bf(fmaxf(val, 0.f));
      } else {
        float mx = val;
#pragma unroll
        for (int o = 32; o >= 1; o >>= 1) mx = fmaxf(mx, __shfl_xor(mx, o));
        float ex = __expf(val - mx);
        float sm = ex;
#pragma unroll
        for (int o = 32; o >= 1; o >>= 1) sm += __shfl_xor(sm, o);
        ((float*)out_v)[(size_t)node * HID + lane] = (val - mx) - logf(sm);
      }
    }
  }
}

// ---------------- launch ----------------
extern "C" void kernel_launch(void* const* d_in, const int* in_sizes, int n_in,
                              void* d_out, int out_size, void* d_ws, size_t ws_size,
                              hipStream_t stream) {
  const float* x   = (const float*)d_in[0];
  const int*   ei  = (const int*)d_in[1];   // int32 (JAX x64 disabled canonicalizes int64)
  const float* W1  = (const float*)d_in[2];
  const float* as1 = (const float*)d_in[3];
  const float* ad1 = (const float*)d_in[4];
  const float* b1  = (const float*)d_in[5];
  const float* W2  = (const float*)d_in[6];
  const float* as2 = (const float*)d_in[7];
  const float* ad2 = (const float*)d_in[8];
  const float* b2  = (const float*)d_in[9];
  float* out = (float*)d_out;

  const int N = NNODE;
  const int E = in_sizes[1] / 2;

  char* base = (char*)d_ws;
  size_t off = 0;
  auto alloc = [&](size_t bytes) -> void* {
    void* p = base + off;
    off += (bytes + 255) & ~(size_t)255;
    return p;
  };
  u16*    hf16   = (u16*)alloc((size_t)N * NC * 2);       // 25.6 MB packed [node][c][h]
  u16*    h1bf   = (u16*)alloc((size_t)MPAD * HID * 2);   // 6.4 MB bf16 layer-1 out (padded)
  u16*    Bp1    = (u16*)alloc((size_t)FIN * NC * 2);     // packed W1
  u16*    Bp2    = (u16*)alloc((size_t)HID * NC * 2);     // packed W2
  float*  al_s   = (float*)alloc((size_t)N * NH * 4);
  float*  al_d   = (float*)alloc((size_t)N * NH * 4);
  int*    deg    = (int*)alloc((size_t)N * 4);
  int*    offs   = (int*)alloc((size_t)(N + 1) * 4);
  int*    cursor = (int*)alloc((size_t)N * 4);
  int*    csr    = (int*)alloc((size_t)E * 4);
  int*    bsums  = (int*)alloc(256 * 4);
  int*    boffs  = (int*)alloc(256 * 4);
  int*    ctrs   = (int*)alloc(2 * 4);                    // work-queue counters (layer 1, 2)

  const int edgeBlocks = (E + 255) / 256;       // 3125
  const int scanBlocks = (N + 255) / 256;       // 196
  const int gemmBlocks = MPAD / 64;             // 782
  const int aggBlocks  = 2048;                  // persistent: 8192 waves = full residency

  // --- init queue counters + CSR build (shared by both layers) ---
  hipMemsetAsync(ctrs, 0, 2 * 4, stream);
  hipMemsetAsync(deg, 0, (size_t)N * 4, stream);
  count_deg<<<edgeBlocks, 256, 0, stream>>>(ei, deg, E);
  scan_phase1<<<scanBlocks, 256, 0, stream>>>(deg, bsums, N);
  scan_phase2<<<1, 256, 0, stream>>>(bsums, boffs, scanBlocks, offs + N);
  scan_phase3<<<scanBlocks, 256, 0, stream>>>(deg, boffs, offs, cursor, N);
  scatter_edges<<<edgeBlocks, 256, 0, stream>>>(ei, cursor, csr, E);

  // --- weight packing ---
  pack_W<<<(FIN * NC + 255) / 256, 256, 0, stream>>>(W1, Bp1, FIN * NC);
  pack_W<<<(HID * NC + 255) / 256, 256, 0, stream>>>(W2, Bp2, HID * NC);

  // --- layer 1 (A = x fp32, converted in-register) ---
  gemm_mfma<4, true><<<gemmBlocks, 256, 0, stream>>>(x, Bp1, as1, ad1, hf16, al_s, al_d, N);
  agg_kernel<false><<<aggBlocks, 256, 0, stream>>>(hf16, (const float4*)al_s, (const float4*)al_d,
                                                   offs, csr, ctrs + 0, b1, h1bf, N);

  // --- layer 2 (A = h1bf bf16) ---
  gemm_mfma<2, false><<<gemmBlocks, 256, 0, stream>>>(h1bf, Bp2, as2, ad2, hf16, al_s, al_d, N);
  agg_kernel<true><<<aggBlocks, 256, 0, stream>>>(hf16, (const float4*)al_s, (const float4*)al_d,
                                                  offs, csr, ctrs + 1, b2, out, N);
}

// Round 10
// 410.326 us; speedup vs baseline: 1.8578x; 1.8578x over previous
//
#include <hip/hip_runtime.h>
#include <math.h>

// Problem constants (GATModel: N=50000, E=800000, F_IN=128, HID=OUT=64, H=4)
constexpr int NNODE = 50000;
constexpr int FIN   = 128;
constexpr int HID   = 64;
constexpr int NH    = 4;
constexpr int NC    = 256;   // NH * HID
constexpr float NEG = 0.2f;
constexpr int MPAD  = 50048; // NNODE padded to 64-row tiles (782*64)

typedef unsigned short u16;
typedef short bf16x8 __attribute__((ext_vector_type(8)));
typedef float f32x4 __attribute__((ext_vector_type(4)));

__device__ __forceinline__ u16 f2bf(float f) {  // round-to-nearest-even
  unsigned int u = __float_as_uint(f);
  return (u16)((u + 0x7FFF + ((u >> 16) & 1)) >> 16);
}
__device__ __forceinline__ float bf2f(u16 h) {
  return __uint_as_float(((unsigned int)h) << 16);
}
__device__ __forceinline__ float readlane_f(float v, int l) {
  return __int_as_float(__builtin_amdgcn_readlane(__float_as_int(v), l));
}

// pack W1[128][256] + W2[64][256] fp32 -> bf16 MFMA B-fragment order in one launch
__global__ __launch_bounds__(256) void pack_W2x(const float* __restrict__ W1, const float* __restrict__ W2,
                                                u16* __restrict__ Bp1, u16* __restrict__ Bp2) {
  int i = blockIdx.x * 256 + threadIdx.x;
  const int t1 = FIN * NC;
  const int t2 = HID * NC;
  if (i < t1) {
    int k = i >> 8, n = i & 255;
    Bp1[((size_t)(k >> 3) * 256 + n) * 8 + (k & 7)] = f2bf(W1[i]);
  } else if (i < t1 + t2) {
    int j = i - t1;
    int k = j >> 8, n = j & 255;
    Bp2[((size_t)(k >> 3) * 256 + n) * 8 + (k & 7)] = f2bf(W2[j]);
  }
}

// ---------------- CSR build (by destination) ----------------
__global__ __launch_bounds__(256) void count_deg(const int* __restrict__ ei, int* __restrict__ deg, int E) {
  int i = blockIdx.x * 256 + threadIdx.x;
  if (i < E) atomicAdd(&deg[ei[E + i]], 1);
}

__global__ __launch_bounds__(256) void scan_phase1(const int* __restrict__ deg,
                                                   int* __restrict__ blockSums, int n) {
  __shared__ int sm[256];
  int tid = threadIdx.x;
  int i = blockIdx.x * 256 + tid;
  sm[tid] = (i < n) ? deg[i] : 0;
  __syncthreads();
#pragma unroll
  for (int o = 128; o > 0; o >>= 1) {
    if (tid < o) sm[tid] += sm[tid + o];
    __syncthreads();
  }
  if (tid == 0) blockSums[blockIdx.x] = sm[0];
}

__global__ __launch_bounds__(256) void scan_phase2(const int* __restrict__ blockSums,
                                                   int* __restrict__ blockOffs, int nb,
                                                   int* __restrict__ total_out) {
  __shared__ int sm[256];
  int tid = threadIdx.x;
  int v = (tid < nb) ? blockSums[tid] : 0;
  sm[tid] = v;
  __syncthreads();
#pragma unroll
  for (int o = 1; o < 256; o <<= 1) {
    int t = (tid >= o) ? sm[tid - o] : 0;
    __syncthreads();
    sm[tid] += t;
    __syncthreads();
  }
  if (tid < nb) blockOffs[tid] = sm[tid] - v;  // exclusive
  if (tid == 255) *total_out = sm[255];        // offs[N] = E
}

__global__ __launch_bounds__(256) void scan_phase3(const int* __restrict__ deg,
                                                   const int* __restrict__ blockOffs,
                                                   int* __restrict__ offs, int* __restrict__ cursor, int n) {
  __shared__ int sm[256];
  int tid = threadIdx.x;
  int i = blockIdx.x * 256 + tid;
  int v = (i < n) ? deg[i] : 0;
  sm[tid] = v;
  __syncthreads();
#pragma unroll
  for (int o = 1; o < 256; o <<= 1) {
    int t = (tid >= o) ? sm[tid - o] : 0;
    __syncthreads();
    sm[tid] += t;
    __syncthreads();
  }
  int ex = sm[tid] - v + blockOffs[blockIdx.x];
  if (i < n) { offs[i] = ex; cursor[i] = ex; }
}

__global__ __launch_bounds__(256) void scatter_edges(const int* __restrict__ ei, int* __restrict__ cursor,
                                                     int* __restrict__ csr_src, int E) {
  int i = blockIdx.x * 256 + threadIdx.x;
  if (i < E) {
    int dst = ei[E + i];
    int pos = atomicAdd(&cursor[dst], 1);
    csr_src[pos] = ei[i];
  }
}

// ---------------- contention-free descending-degree counting sort ----------------
// R8 lesson: global atomics on 64 hot lines cost ~10ns serialized each -> 130us.
// Here: per-block LDS histograms (plain global stores), a 64-lane offset kernel,
// and an LDS-cursor scatter. Zero global atomics.
__global__ __launch_bounds__(256) void hist_block(const int* __restrict__ deg,
                                                  int* __restrict__ blockHist, int n) {
  __shared__ int h[64];
  int tid = threadIdx.x;
  if (tid < 64) h[tid] = 0;
  __syncthreads();
  int i = blockIdx.x * 256 + tid;
  if (i < n) atomicAdd(&h[min(deg[i], 63)], 1);   // LDS atomic: fast
  __syncthreads();
  if (tid < 64) blockHist[blockIdx.x * 64 + tid] = h[tid];
}

__global__ __launch_bounds__(64) void bin_offsets(const int* __restrict__ blockHist,
                                                  int* __restrict__ blockOff,
                                                  int* __restrict__ base, int nb) {
  int d = threadIdx.x;  // one lane per degree-bin
  int run = 0;
  for (int b = 0; b < nb; ++b) {                  // 196 serial adds per lane: trivial
    int v = blockHist[b * 64 + d];
    blockOff[b * 64 + d] = run;
    run += v;
  }
  int incl = run;                                  // inclusive ascending prefix of totals
#pragma unroll
  for (int o = 1; o < 64; o <<= 1) {
    int t = __shfl_up(incl, o);
    if (d >= o) incl += t;
  }
  int allsum = __shfl(incl, 63);
  base[d] = allsum - incl;                         // sum of bins > d => DESCENDING order
}

__global__ __launch_bounds__(256) void scatter_sorted(const int* __restrict__ deg,
                                                      const int* __restrict__ blockOff,
                                                      const int* __restrict__ base,
                                                      int* __restrict__ sorted, int n) {
  __shared__ int cur[64];
  int tid = threadIdx.x;
  if (tid < 64) cur[tid] = base[tid] + blockOff[blockIdx.x * 64 + tid];
  __syncthreads();
  int i = blockIdx.x * 256 + tid;
  if (i < n) {
    int bin = min(deg[i], 63);
    int pos = atomicAdd(&cur[bin], 1);             // LDS atomic: fast
    sorted[pos] = i;
  }
}

// ---------------- MFMA bf16 GEMM + alpha + packed bf16 store ----------------
// C[M,256] = A[M,K] @ B[K,256]bf16 (B pre-packed in fragment order).
// A-frag: lane holds A[m = lane&15][k = (lane>>4)*8 + j]
// B-frag: lane holds B[k = (lane>>4)*8 + j][n = lane&15]  (packed Bp)
// D: col = lane&15, row = (lane>>4)*4 + reg   [m89/m91-verified layouts]
template <int KS, bool AF32>  // K = 32*KS
__global__ __launch_bounds__(256) void gemm_mfma(
    const void* __restrict__ Aptr, const u16* __restrict__ Bp,
    const float* __restrict__ a_s, const float* __restrict__ a_d,
    u16* __restrict__ hf16, float* __restrict__ al_s, float* __restrict__ al_d, int M) {
  const int K = 32 * KS;
  int lane = threadIdx.x & 63;
  int wv = threadIdx.x >> 6;
  int q = lane >> 4, r = lane & 15;
  int m0 = blockIdx.x * 64 + wv * 16;

  bf16x8 af[KS];
  if (AF32) {
    int ar = m0 + r; if (ar >= M) ar = M - 1;   // x has exactly M rows; clamp (stores guarded)
    const float* arow = (const float*)Aptr + (size_t)ar * K + q * 8;
#pragma unroll
    for (int ks = 0; ks < KS; ++ks) {
      float4 v0 = *(const float4*)(arow + ks * 32);
      float4 v1 = *(const float4*)(arow + ks * 32 + 4);
      bf16x8 t;
      t[0] = (short)f2bf(v0.x); t[1] = (short)f2bf(v0.y);
      t[2] = (short)f2bf(v0.z); t[3] = (short)f2bf(v0.w);
      t[4] = (short)f2bf(v1.x); t[5] = (short)f2bf(v1.y);
      t[6] = (short)f2bf(v1.z); t[7] = (short)f2bf(v1.w);
      af[ks] = t;
    }
  } else {
    const u16* arow = (const u16*)Aptr + (size_t)(m0 + r) * K + q * 8;  // padded buffer
#pragma unroll
    for (int ks = 0; ks < KS; ++ks) af[ks] = *(const bf16x8*)(arow + ks * 32);
  }

  int node_base = m0 + q * 4;
#pragma unroll
  for (int h = 0; h < NH; ++h) {
    f32x4 acc[4];
#pragma unroll
    for (int c4 = 0; c4 < 4; ++c4) {
      acc[c4] = (f32x4){0.f, 0.f, 0.f, 0.f};
      const u16* bp = Bp + ((size_t)q * 256 + (h * 4 + c4) * 16 + r) * 8;
#pragma unroll
      for (int ks = 0; ks < KS; ++ks) {
        bf16x8 bf = *(const bf16x8*)(bp + (size_t)ks * 4 * 256 * 8);
        acc[c4] = __builtin_amdgcn_mfma_f32_16x16x32_bf16(af[ks], bf, acc[c4], 0, 0, 0);
      }
    }
    // epilogue for this head: alpha partials + packed bf16 stores
    float ps[4] = {0.f, 0.f, 0.f, 0.f}, pd[4] = {0.f, 0.f, 0.f, 0.f};
#pragma unroll
    for (int c4 = 0; c4 < 4; ++c4) {
      float sa = a_s[h * HID + c4 * 16 + r];
      float da = a_d[h * HID + c4 * 16 + r];
#pragma unroll
      for (int reg = 0; reg < 4; ++reg) {
        float v = acc[c4][reg];
        ps[reg] += v * sa;
        pd[reg] += v * da;
        int node = node_base + reg;
        if (node < M) hf16[(size_t)node * NC + (c4 * 16 + r) * NH + h] = f2bf(v);
      }
    }
#pragma unroll
    for (int reg = 0; reg < 4; ++reg) {
#pragma unroll
      for (int o = 1; o < 16; o <<= 1) {
        ps[reg] += __shfl_xor(ps[reg], o);
        pd[reg] += __shfl_xor(pd[reg], o);
      }
      int node = node_base + reg;
      if (r == 0 && node < M) {
        al_s[node * NH + h] = ps[reg];
        al_d[node * NH + h] = pd[reg];
      }
    }
  }
}

// ---------------- aggregation: one wave per destination node ----------------
// Static assignment from the DESCENDING-degree sorted list (big nodes start
// first, drain tail is tiny nodes); 128-thread blocks (2 waves) halve the
// WG-granularity imbalance. Mask-padded chunks of 8, depth-1 pipeline on the
// gathers, denom via shfl tree. No max-shift: logits bounded ~|e|<20 =>
// exp(e)/sum identical to reference's shifted softmax.
template <bool FINAL>
__global__ __launch_bounds__(128) void agg_kernel(const u16* __restrict__ hf16,
                                                  const float4* __restrict__ al_s4,
                                                  const float4* __restrict__ al_d4,
                                                  const int* __restrict__ offs, const int* __restrict__ csr_src,
                                                  const int* __restrict__ sorted,
                                                  const float* __restrict__ bias, void* __restrict__ out_v, int n) {
  int lane = threadIdx.x & 63;
  int idx = blockIdx.x * 2 + (threadIdx.x >> 6);
  if (idx >= n) return;
  int node = sorted[idx];
  float4 ad = al_d4[node];
  int lj = lane & 7;           // edge slot within chunk (weight lanes)
  int hsel = (lane >> 3) & 3;  // head handled by this lane in the weight phase
  float adv = hsel == 0 ? ad.x : (hsel == 1 ? ad.y : (hsel == 2 ? ad.z : ad.w));
  float c0 = 0.f, c1 = 0.f, c2 = 0.f, c3 = 0.f;
  float dacc = 0.f;            // per-head denom partial on lanes 0,8,16,24
  int s = offs[node], e = offs[node + 1];
  int nch = (e - s + 7) >> 3;
  int i = s;

  int vidx = 0;
  float4 as = make_float4(0.f, 0.f, 0.f, 0.f);
  ushort4 hv[8];
  if (nch > 0) {
    int id0 = i + lj; if (id0 >= e) id0 = e - 1;   // clamp: masked by w=0 later
    vidx = csr_src[id0];
    as = al_s4[vidx];
#pragma unroll
    for (int j = 0; j < 8; ++j) {
      int sa = __builtin_amdgcn_readlane(vidx, j);
      hv[j] = ((const ushort4*)(hf16 + (size_t)sa * NC))[lane];
    }
  }

  for (int ch = 0; ch < nch; ++ch) {
    bool last = (ch + 1 == nch);
    // ---- weight phase (lanes 0..31 meaningful) ----
    float asv = hsel == 0 ? as.x : (hsel == 1 ? as.y : (hsel == 2 ? as.z : as.w));
    float ev = asv + adv;
    ev = ev >= 0.f ? ev : NEG * ev;
    float wv = __expf(ev);
    if (i + lj >= e) wv = 0.f;                     // mask padded slots
    float t = wv;
    t += __shfl_xor(t, 1); t += __shfl_xor(t, 2); t += __shfl_xor(t, 4);
    dacc += t;                                     // lanes 0,8,16,24 hold head sums
    // ---- prefetch next chunk ----
    int vidx_n = 0;
    float4 as_n = make_float4(0.f, 0.f, 0.f, 0.f);
    ushort4 hn[8];
    if (!last) {
      int id1 = i + 8 + lj; if (id1 >= e) id1 = e - 1;
      vidx_n = csr_src[id1];
      as_n = al_s4[vidx_n];
#pragma unroll
      for (int j = 0; j < 8; ++j) {
        int sa = __builtin_amdgcn_readlane(vidx_n, j);
        hn[j] = ((const ushort4*)(hf16 + (size_t)sa * NC))[lane];
      }
    }
    // ---- accumulate current chunk ----
#pragma unroll
    for (int j = 0; j < 8; ++j) {
      float wx = readlane_f(wv, j);
      float wy = readlane_f(wv, 8 + j);
      float wz = readlane_f(wv, 16 + j);
      float ww = readlane_f(wv, 24 + j);
      c0 += wx * bf2f(hv[j].x);
      c1 += wy * bf2f(hv[j].y);
      c2 += wz * bf2f(hv[j].z);
      c3 += ww * bf2f(hv[j].w);
    }
    if (!last) {
      vidx = vidx_n; as = as_n;
#pragma unroll
      for (int j = 0; j < 8; ++j) hv[j] = hn[j];
    }
    i += 8;
  }
  float d0 = readlane_f(dacc, 0), d1 = readlane_f(dacc, 8);
  float d2 = readlane_f(dacc, 16), d3 = readlane_f(dacc, 24);
  float val = 0.25f * (c0 / (d0 + 1e-16f) + c1 / (d1 + 1e-16f) +
                       c2 / (d2 + 1e-16f) + c3 / (d3 + 1e-16f)) + bias[lane];
  if (!FINAL) {
    // layer-1 output: relu + bf16 (feeds layer-2 MFMA GEMM directly)
    ((u16*)out_v)[(size_t)node * HID + lane] = f2bf(fmaxf(val, 0.f));
  } else {
    float mx = val;
#pragma unroll
    for (int o = 32; o >= 1; o >>= 1) mx = fmaxf(mx, __shfl_xor(mx, o));
    float ex = __expf(val - mx);
    float sm = ex;
#pragma unroll
    for (int o = 32; o >= 1; o >>= 1) sm += __shfl_xor(sm, o);
    ((float*)out_v)[(size_t)node * HID + lane] = (val - mx) - logf(sm);
  }
}

// ---------------- launch ----------------
extern "C" void kernel_launch(void* const* d_in, const int* in_sizes, int n_in,
                              void* d_out, int out_size, void* d_ws, size_t ws_size,
                              hipStream_t stream) {
  const float* x   = (const float*)d_in[0];
  const int*   ei  = (const int*)d_in[1];   // int32 (JAX x64 disabled canonicalizes int64)
  const float* W1  = (const float*)d_in[2];
  const float* as1 = (const float*)d_in[3];
  const float* ad1 = (const float*)d_in[4];
  const float* b1  = (const float*)d_in[5];
  const float* W2  = (const float*)d_in[6];
  const float* as2 = (const float*)d_in[7];
  const float* ad2 = (const float*)d_in[8];
  const float* b2  = (const float*)d_in[9];
  float* out = (float*)d_out;

  const int N = NNODE;
  const int E = in_sizes[1] / 2;

  char* base = (char*)d_ws;
  size_t off = 0;
  auto alloc = [&](size_t bytes) -> void* {
    void* p = base + off;
    off += (bytes + 255) & ~(size_t)255;
    return p;
  };
  u16*    hf16   = (u16*)alloc((size_t)N * NC * 2);       // 25.6 MB packed [node][c][h]
  u16*    h1bf   = (u16*)alloc((size_t)MPAD * HID * 2);   // 6.4 MB bf16 layer-1 out (padded)
  u16*    Bp1    = (u16*)alloc((size_t)FIN * NC * 2);     // packed W1
  u16*    Bp2    = (u16*)alloc((size_t)HID * NC * 2);     // packed W2
  float*  al_s   = (float*)alloc((size_t)N * NH * 4);
  float*  al_d   = (float*)alloc((size_t)N * NH * 4);
  int*    deg    = (int*)alloc((size_t)N * 4);
  int*    offs   = (int*)alloc((size_t)(N + 1) * 4);
  int*    cursor = (int*)alloc((size_t)N * 4);
  int*    csr    = (int*)alloc((size_t)E * 4);
  int*    sorted = (int*)alloc((size_t)N * 4);
  int*    bsums  = (int*)alloc(256 * 4);
  int*    boffs  = (int*)alloc(256 * 4);
  int*    bHist  = (int*)alloc((size_t)196 * 64 * 4);     // per-block degree histograms
  int*    bOff   = (int*)alloc((size_t)196 * 64 * 4);     // per-(block,bin) offsets
  int*    binBase= (int*)alloc(64 * 4);                   // per-bin bases (descending)

  const int edgeBlocks = (E + 255) / 256;       // 3125
  const int scanBlocks = (N + 255) / 256;       // 196
  const int gemmBlocks = MPAD / 64;             // 782
  const int aggBlocks  = (N + 1) / 2;           // 25000 blocks x 2 waves

  // --- CSR build + contention-free degree sort (shared by both layers) ---
  hipMemsetAsync(deg, 0, (size_t)N * 4, stream);
  count_deg<<<edgeBlocks, 256, 0, stream>>>(ei, deg, E);
  scan_phase1<<<scanBlocks, 256, 0, stream>>>(deg, bsums, N);
  hist_block<<<scanBlocks, 256, 0, stream>>>(deg, bHist, N);
  scan_phase2<<<1, 256, 0, stream>>>(bsums, boffs, scanBlocks, offs + N);
  bin_offsets<<<1, 64, 0, stream>>>(bHist, bOff, binBase, scanBlocks);
  scan_phase3<<<scanBlocks, 256, 0, stream>>>(deg, boffs, offs, cursor, N);
  scatter_sorted<<<scanBlocks, 256, 0, stream>>>(deg, bOff, binBase, sorted, N);
  scatter_edges<<<edgeBlocks, 256, 0, stream>>>(ei, cursor, csr, E);

  // --- weight packing (both layers, one launch) ---
  pack_W2x<<<(FIN * NC + HID * NC + 255) / 256, 256, 0, stream>>>(W1, W2, Bp1, Bp2);

  // --- layer 1 (A = x fp32, converted in-register) ---
  gemm_mfma<4, true><<<gemmBlocks, 256, 0, stream>>>(x, Bp1, as1, ad1, hf16, al_s, al_d, N);
  agg_kernel<false><<<aggBlocks, 128, 0, stream>>>(hf16, (const float4*)al_s, (const float4*)al_d,
                                                   offs, csr, sorted, b1, h1bf, N);

  // --- layer 2 (A = h1bf bf16) ---
  gemm_mfma<2, false><<<gemmBlocks, 256, 0, stream>>>(h1bf, Bp2, as2, ad2, hf16, al_s, al_d, N);
  agg_kernel<true><<<aggBlocks, 128, 0, stream>>>(hf16, (const float4*)al_s, (const float4*)al_d,
                                                  offs, csr, sorted, b2, out, N);
}

// Round 11
// 338.912 us; speedup vs baseline: 2.2492x; 1.2107x over previous
//
#include <hip/hip_runtime.h>
#include <math.h>

// Problem constants (GATModel: N=50000, E=800000, F_IN=128, HID=OUT=64, H=4)
constexpr int NNODE = 50000;
constexpr int FIN   = 128;
constexpr int HID   = 64;
constexpr int NH    = 4;
constexpr int NC    = 256;   // NH * HID
constexpr float NEG = 0.2f;
constexpr int MPAD  = 50048; // NNODE padded to 64-row tiles (782*64)

typedef unsigned short u16;
typedef short bf16x8 __attribute__((ext_vector_type(8)));
typedef float f32x4 __attribute__((ext_vector_type(4)));

__device__ __forceinline__ u16 f2bf(float f) {  // round-to-nearest-even
  unsigned int u = __float_as_uint(f);
  return (u16)((u + 0x7FFF + ((u >> 16) & 1)) >> 16);
}
__device__ __forceinline__ float bf2f(u16 h) {
  return __uint_as_float(((unsigned int)h) << 16);
}
__device__ __forceinline__ float readlane_f(float v, int l) {
  return __int_as_float(__builtin_amdgcn_readlane(__float_as_int(v), l));
}

// pack W1[128][256] + W2[64][256] fp32 -> bf16 MFMA B-fragment order in one launch
__global__ __launch_bounds__(256) void pack_W2x(const float* __restrict__ W1, const float* __restrict__ W2,
                                                u16* __restrict__ Bp1, u16* __restrict__ Bp2) {
  int i = blockIdx.x * 256 + threadIdx.x;
  const int t1 = FIN * NC;
  const int t2 = HID * NC;
  if (i < t1) {
    int k = i >> 8, n = i & 255;
    Bp1[((size_t)(k >> 3) * 256 + n) * 8 + (k & 7)] = f2bf(W1[i]);
  } else if (i < t1 + t2) {
    int j = i - t1;
    int k = j >> 8, n = j & 255;
    Bp2[((size_t)(k >> 3) * 256 + n) * 8 + (k & 7)] = f2bf(W2[j]);
  }
}

// ---------------- CSR build (by destination) ----------------
// count_deg also records each edge's arrival rank within its dst bucket
// (the atomic's return value — previously discarded). scatter_edges is then
// atomic-free: pos = offs[dst] + rank.
__global__ __launch_bounds__(256) void count_deg(const int* __restrict__ ei, int* __restrict__ deg,
                                                 int* __restrict__ rank, int E) {
  int i = blockIdx.x * 256 + threadIdx.x;
  if (i < E) rank[i] = atomicAdd(&deg[ei[E + i]], 1);
}

__global__ __launch_bounds__(256) void scan_phase1(const int* __restrict__ deg,
                                                   int* __restrict__ blockSums, int n) {
  __shared__ int sm[256];
  int tid = threadIdx.x;
  int i = blockIdx.x * 256 + tid;
  sm[tid] = (i < n) ? deg[i] : 0;
  __syncthreads();
#pragma unroll
  for (int o = 128; o > 0; o >>= 1) {
    if (tid < o) sm[tid] += sm[tid + o];
    __syncthreads();
  }
  if (tid == 0) blockSums[blockIdx.x] = sm[0];
}

__global__ __launch_bounds__(256) void scan_phase2(const int* __restrict__ blockSums,
                                                   int* __restrict__ blockOffs, int nb,
                                                   int* __restrict__ total_out) {
  __shared__ int sm[256];
  int tid = threadIdx.x;
  int v = (tid < nb) ? blockSums[tid] : 0;
  sm[tid] = v;
  __syncthreads();
#pragma unroll
  for (int o = 1; o < 256; o <<= 1) {
    int t = (tid >= o) ? sm[tid - o] : 0;
    __syncthreads();
    sm[tid] += t;
    __syncthreads();
  }
  if (tid < nb) blockOffs[tid] = sm[tid] - v;  // exclusive
  if (tid == 255) *total_out = sm[255];        // offs[N] = E
}

__global__ __launch_bounds__(256) void scan_phase3(const int* __restrict__ deg,
                                                   const int* __restrict__ blockOffs,
                                                   int* __restrict__ offs, int n) {
  __shared__ int sm[256];
  int tid = threadIdx.x;
  int i = blockIdx.x * 256 + tid;
  int v = (i < n) ? deg[i] : 0;
  sm[tid] = v;
  __syncthreads();
#pragma unroll
  for (int o = 1; o < 256; o <<= 1) {
    int t = (tid >= o) ? sm[tid - o] : 0;
    __syncthreads();
    sm[tid] += t;
    __syncthreads();
  }
  int ex = sm[tid] - v + blockOffs[blockIdx.x];
  if (i < n) offs[i] = ex;
}

__global__ __launch_bounds__(256) void scatter_edges(const int* __restrict__ ei,
                                                     const int* __restrict__ offs,
                                                     const int* __restrict__ rank,
                                                     int* __restrict__ csr_src, int E) {
  int i = blockIdx.x * 256 + threadIdx.x;
  if (i < E) {
    int dst = ei[E + i];
    csr_src[offs[dst] + rank[i]] = ei[i];   // no atomic
  }
}

// ---------------- MFMA bf16 GEMM + alpha + packed bf16 store ----------------
// C[M,256] = A[M,K] @ B[K,256]bf16 (B pre-packed in fragment order).
// A-frag: lane holds A[m = lane&15][k = (lane>>4)*8 + j]
// B-frag: lane holds B[k = (lane>>4)*8 + j][n = lane&15]  (packed Bp)
// D: col = lane&15, row = (lane>>4)*4 + reg   [m89/m91-verified layouts]
template <int KS, bool AF32>  // K = 32*KS
__global__ __launch_bounds__(256) void gemm_mfma(
    const void* __restrict__ Aptr, const u16* __restrict__ Bp,
    const float* __restrict__ a_s, const float* __restrict__ a_d,
    u16* __restrict__ hf16, float* __restrict__ al_s, float* __restrict__ al_d, int M) {
  const int K = 32 * KS;
  int lane = threadIdx.x & 63;
  int wv = threadIdx.x >> 6;
  int q = lane >> 4, r = lane & 15;
  int m0 = blockIdx.x * 64 + wv * 16;

  bf16x8 af[KS];
  if (AF32) {
    int ar = m0 + r; if (ar >= M) ar = M - 1;   // x has exactly M rows; clamp (stores guarded)
    const float* arow = (const float*)Aptr + (size_t)ar * K + q * 8;
#pragma unroll
    for (int ks = 0; ks < KS; ++ks) {
      float4 v0 = *(const float4*)(arow + ks * 32);
      float4 v1 = *(const float4*)(arow + ks * 32 + 4);
      bf16x8 t;
      t[0] = (short)f2bf(v0.x); t[1] = (short)f2bf(v0.y);
      t[2] = (short)f2bf(v0.z); t[3] = (short)f2bf(v0.w);
      t[4] = (short)f2bf(v1.x); t[5] = (short)f2bf(v1.y);
      t[6] = (short)f2bf(v1.z); t[7] = (short)f2bf(v1.w);
      af[ks] = t;
    }
  } else {
    const u16* arow = (const u16*)Aptr + (size_t)(m0 + r) * K + q * 8;  // padded buffer
#pragma unroll
    for (int ks = 0; ks < KS; ++ks) af[ks] = *(const bf16x8*)(arow + ks * 32);
  }

  int node_base = m0 + q * 4;
#pragma unroll
  for (int h = 0; h < NH; ++h) {
    f32x4 acc[4];
#pragma unroll
    for (int c4 = 0; c4 < 4; ++c4) {
      acc[c4] = (f32x4){0.f, 0.f, 0.f, 0.f};
      const u16* bp = Bp + ((size_t)q * 256 + (h * 4 + c4) * 16 + r) * 8;
#pragma unroll
      for (int ks = 0; ks < KS; ++ks) {
        bf16x8 bf = *(const bf16x8*)(bp + (size_t)ks * 4 * 256 * 8);
        acc[c4] = __builtin_amdgcn_mfma_f32_16x16x32_bf16(af[ks], bf, acc[c4], 0, 0, 0);
      }
    }
    // epilogue for this head: alpha partials + packed bf16 stores
    float ps[4] = {0.f, 0.f, 0.f, 0.f}, pd[4] = {0.f, 0.f, 0.f, 0.f};
#pragma unroll
    for (int c4 = 0; c4 < 4; ++c4) {
      float sa = a_s[h * HID + c4 * 16 + r];
      float da = a_d[h * HID + c4 * 16 + r];
#pragma unroll
      for (int reg = 0; reg < 4; ++reg) {
        float v = acc[c4][reg];
        ps[reg] += v * sa;
        pd[reg] += v * da;
        int node = node_base + reg;
        if (node < M) hf16[(size_t)node * NC + (c4 * 16 + r) * NH + h] = f2bf(v);
      }
    }
#pragma unroll
    for (int reg = 0; reg < 4; ++reg) {
#pragma unroll
      for (int o = 1; o < 16; o <<= 1) {
        ps[reg] += __shfl_xor(ps[reg], o);
        pd[reg] += __shfl_xor(pd[reg], o);
      }
      int node = node_base + reg;
      if (r == 0 && node < M) {
        al_s[node * NH + h] = ps[reg];
        al_d[node * NH + h] = pd[reg];
      }
    }
  }
}

// ---------------- aggregation: persistent waves, static node stride ----------------
// 8192 resident waves (full chip); wave w handles nodes w, w+8192, ... (~6 each,
// Poisson-averaged balance, NO atomics — R9's queue atomic cost 200us).
// Per node: mask-padded chunks of 8, depth-1 pipeline on gathers, denom via
// shfl tree. No max-shift: logits bounded ~|e|<20 => exp(e)/sum identical to
// reference's shifted softmax.
template <bool FINAL>
__global__ __launch_bounds__(256) void agg_kernel(const u16* __restrict__ hf16,
                                                  const float4* __restrict__ al_s4,
                                                  const float4* __restrict__ al_d4,
                                                  const int* __restrict__ offs, const int* __restrict__ csr_src,
                                                  const float* __restrict__ bias, void* __restrict__ out_v, int n) {
  int lane = threadIdx.x & 63;
  int wid = blockIdx.x * 4 + (threadIdx.x >> 6);
  int nwaves = gridDim.x * 4;
  int lj = lane & 7;           // edge slot within chunk (weight lanes)
  int hsel = (lane >> 3) & 3;  // head handled by this lane in the weight phase
  float bi = bias[lane];

  for (int node = wid; node < n; node += nwaves) {
    float4 ad = al_d4[node];
    float adv = hsel == 0 ? ad.x : (hsel == 1 ? ad.y : (hsel == 2 ? ad.z : ad.w));
    float c0 = 0.f, c1 = 0.f, c2 = 0.f, c3 = 0.f;
    float dacc = 0.f;          // per-head denom partial on lanes 0,8,16,24
    int s = offs[node], e = offs[node + 1];
    int nch = (e - s + 7) >> 3;
    int i = s;

    int vidx = 0;
    float4 as = make_float4(0.f, 0.f, 0.f, 0.f);
    ushort4 hv[8];
    if (nch > 0) {
      int id0 = i + lj; if (id0 >= e) id0 = e - 1;  // clamp: masked by w=0 later
      vidx = csr_src[id0];
      as = al_s4[vidx];
#pragma unroll
      for (int j = 0; j < 8; ++j) {
        int sa = __builtin_amdgcn_readlane(vidx, j);
        hv[j] = ((const ushort4*)(hf16 + (size_t)sa * NC))[lane];
      }
    }

    for (int ch = 0; ch < nch; ++ch) {
      bool last = (ch + 1 == nch);
      // ---- weight phase (lanes 0..31 meaningful) ----
      float asv = hsel == 0 ? as.x : (hsel == 1 ? as.y : (hsel == 2 ? as.z : as.w));
      float ev = asv + adv;
      ev = ev >= 0.f ? ev : NEG * ev;
      float wv = __expf(ev);
      if (i + lj >= e) wv = 0.f;                   // mask padded slots
      float t = wv;
      t += __shfl_xor(t, 1); t += __shfl_xor(t, 2); t += __shfl_xor(t, 4);
      dacc += t;                                   // lanes 0,8,16,24 hold head sums
      // ---- prefetch next chunk ----
      int vidx_n = 0;
      float4 as_n = make_float4(0.f, 0.f, 0.f, 0.f);
      ushort4 hn[8];
      if (!last) {
        int id1 = i + 8 + lj; if (id1 >= e) id1 = e - 1;
        vidx_n = csr_src[id1];
        as_n = al_s4[vidx_n];
#pragma unroll
        for (int j = 0; j < 8; ++j) {
          int sa = __builtin_amdgcn_readlane(vidx_n, j);
          hn[j] = ((const ushort4*)(hf16 + (size_t)sa * NC))[lane];
        }
      }
      // ---- accumulate current chunk ----
#pragma unroll
      for (int j = 0; j < 8; ++j) {
        float wx = readlane_f(wv, j);
        float wy = readlane_f(wv, 8 + j);
        float wz = readlane_f(wv, 16 + j);
        float ww = readlane_f(wv, 24 + j);
        c0 += wx * bf2f(hv[j].x);
        c1 += wy * bf2f(hv[j].y);
        c2 += wz * bf2f(hv[j].z);
        c3 += ww * bf2f(hv[j].w);
      }
      if (!last) {
        vidx = vidx_n; as = as_n;
#pragma unroll
        for (int j = 0; j < 8; ++j) hv[j] = hn[j];
      }
      i += 8;
    }
    float d0 = readlane_f(dacc, 0), d1 = readlane_f(dacc, 8);
    float d2 = readlane_f(dacc, 16), d3 = readlane_f(dacc, 24);
    float val = 0.25f * (c0 / (d0 + 1e-16f) + c1 / (d1 + 1e-16f) +
                         c2 / (d2 + 1e-16f) + c3 / (d3 + 1e-16f)) + bi;
    if (!FINAL) {
      // layer-1 output: relu + bf16 (feeds layer-2 MFMA GEMM directly)
      ((u16*)out_v)[(size_t)node * HID + lane] = f2bf(fmaxf(val, 0.f));
    } else {
      float mx = val;
#pragma unroll
      for (int o = 32; o >= 1; o >>= 1) mx = fmaxf(mx, __shfl_xor(mx, o));
      float ex = __expf(val - mx);
      float sm = ex;
#pragma unroll
      for (int o = 32; o >= 1; o >>= 1) sm += __shfl_xor(sm, o);
      ((float*)out_v)[(size_t)node * HID + lane] = (val - mx) - logf(sm);
    }
  }
}

// ---------------- launch ----------------
extern "C" void kernel_launch(void* const* d_in, const int* in_sizes, int n_in,
                              void* d_out, int out_size, void* d_ws, size_t ws_size,
                              hipStream_t stream) {
  const float* x   = (const float*)d_in[0];
  const int*   ei  = (const int*)d_in[1];   // int32 (JAX x64 disabled canonicalizes int64)
  const float* W1  = (const float*)d_in[2];
  const float* as1 = (const float*)d_in[3];
  const float* ad1 = (const float*)d_in[4];
  const float* b1  = (const float*)d_in[5];
  const float* W2  = (const float*)d_in[6];
  const float* as2 = (const float*)d_in[7];
  const float* ad2 = (const float*)d_in[8];
  const float* b2  = (const float*)d_in[9];
  float* out = (float*)d_out;

  const int N = NNODE;
  const int E = in_sizes[1] / 2;

  char* base = (char*)d_ws;
  size_t off = 0;
  auto alloc = [&](size_t bytes) -> void* {
    void* p = base + off;
    off += (bytes + 255) & ~(size_t)255;
    return p;
  };
  u16*    hf16   = (u16*)alloc((size_t)N * NC * 2);       // 25.6 MB packed [node][c][h]
  u16*    h1bf   = (u16*)alloc((size_t)MPAD * HID * 2);   // 6.4 MB bf16 layer-1 out (padded)
  u16*    Bp1    = (u16*)alloc((size_t)FIN * NC * 2);     // packed W1
  u16*    Bp2    = (u16*)alloc((size_t)HID * NC * 2);     // packed W2
  float*  al_s   = (float*)alloc((size_t)N * NH * 4);
  float*  al_d   = (float*)alloc((size_t)N * NH * 4);
  int*    deg    = (int*)alloc((size_t)N * 4);
  int*    offs   = (int*)alloc((size_t)(N + 1) * 4);
  int*    rank   = (int*)alloc((size_t)E * 4);
  int*    csr    = (int*)alloc((size_t)E * 4);
  int*    bsums  = (int*)alloc(256 * 4);
  int*    boffs  = (int*)alloc(256 * 4);

  const int edgeBlocks = (E + 255) / 256;       // 3125
  const int scanBlocks = (N + 255) / 256;       // 196
  const int gemmBlocks = MPAD / 64;             // 782
  const int aggBlocks  = 2048;                  // 8192 persistent waves = full residency

  // --- CSR build (shared by both layers) ---
  hipMemsetAsync(deg, 0, (size_t)N * 4, stream);
  count_deg<<<edgeBlocks, 256, 0, stream>>>(ei, deg, rank, E);
  scan_phase1<<<scanBlocks, 256, 0, stream>>>(deg, bsums, N);
  scan_phase2<<<1, 256, 0, stream>>>(bsums, boffs, scanBlocks, offs + N);
  scan_phase3<<<scanBlocks, 256, 0, stream>>>(deg, boffs, offs, N);
  scatter_edges<<<edgeBlocks, 256, 0, stream>>>(ei, offs, rank, csr, E);

  // --- weight packing (both layers, one launch) ---
  pack_W2x<<<(FIN * NC + HID * NC + 255) / 256, 256, 0, stream>>>(W1, W2, Bp1, Bp2);

  // --- layer 1 (A = x fp32, converted in-register) ---
  gemm_mfma<4, true><<<gemmBlocks, 256, 0, stream>>>(x, Bp1, as1, ad1, hf16, al_s, al_d, N);
  agg_kernel<false><<<aggBlocks, 256, 0, stream>>>(hf16, (const float4*)al_s, (const float4*)al_d,
                                                   offs, csr, b1, h1bf, N);

  // --- layer 2 (A = h1bf bf16) ---
  gemm_mfma<2, false><<<gemmBlocks, 256, 0, stream>>>(h1bf, Bp2, as2, ad2, hf16, al_s, al_d, N);
  agg_kernel<true><<<aggBlocks, 256, 0, stream>>>(hf16, (const float4*)al_s, (const float4*)al_d,
                                                  offs, csr, b2, out, N);
}

// Round 12
// 320.212 us; speedup vs baseline: 2.3806x; 1.0584x over previous
//
#include <hip/hip_runtime.h>
#include <math.h>

// Problem constants (GATModel: N=50000, E=800000, F_IN=128, HID=OUT=64, H=4)
constexpr int NNODE = 50000;
constexpr int FIN   = 128;
constexpr int HID   = 64;
constexpr int NH    = 4;
constexpr int NC    = 256;   // NH * HID
constexpr float NEG = 0.2f;
constexpr int MPAD  = 50048; // NNODE padded to 64-row tiles (782*64)
constexpr int SCANB = (NNODE + 255) / 256;  // 196

typedef unsigned short u16;
typedef short bf16x8 __attribute__((ext_vector_type(8)));
typedef float f32x4 __attribute__((ext_vector_type(4)));

__device__ __forceinline__ u16 f2bf(float f) {  // round-to-nearest-even
  unsigned int u = __float_as_uint(f);
  return (u16)((u + 0x7FFF + ((u >> 16) & 1)) >> 16);
}
__device__ __forceinline__ float bf2f(u16 h) {
  return __uint_as_float(((unsigned int)h) << 16);
}
__device__ __forceinline__ float readlane_f(float v, int l) {
  return __int_as_float(__builtin_amdgcn_readlane(__float_as_int(v), l));
}

// ---------------- CSR build (by destination) ----------------
// count_deg also records each edge's arrival rank within its dst bucket
// (the atomic's return value). scatter_edges is then atomic-free.
__global__ __launch_bounds__(256) void count_deg(const int* __restrict__ ei, int* __restrict__ deg,
                                                 int* __restrict__ rank, int E) {
  int i = blockIdx.x * 256 + threadIdx.x;
  if (i < E) rank[i] = atomicAdd(&deg[ei[E + i]], 1);
}

// Fused: blocks [0,SCANB) do scan phase-1 block sums; blocks [SCANB,...) pack
// W1/W2 fp32 -> bf16 MFMA B-fragment order (independent work, one launch).
__global__ __launch_bounds__(256) void scan1_pack(const int* __restrict__ deg,
                                                  int* __restrict__ blockSums, int n,
                                                  const float* __restrict__ W1, const float* __restrict__ W2,
                                                  u16* __restrict__ Bp1, u16* __restrict__ Bp2) {
  int b = blockIdx.x;
  int tid = threadIdx.x;
  if (b < SCANB) {
    __shared__ int sm[256];
    int i = b * 256 + tid;
    sm[tid] = (i < n) ? deg[i] : 0;
    __syncthreads();
#pragma unroll
    for (int o = 128; o > 0; o >>= 1) {
      if (tid < o) sm[tid] += sm[tid + o];
      __syncthreads();
    }
    if (tid == 0) blockSums[b] = sm[0];
  } else {
    int i = (b - SCANB) * 256 + tid;
    const int t1 = FIN * NC;
    const int t2 = HID * NC;
    if (i < t1) {
      int k = i >> 8, c = i & 255;
      Bp1[((size_t)(k >> 3) * 256 + c) * 8 + (k & 7)] = f2bf(W1[i]);
    } else if (i < t1 + t2) {
      int j = i - t1;
      int k = j >> 8, c = j & 255;
      Bp2[((size_t)(k >> 3) * 256 + c) * 8 + (k & 7)] = f2bf(W2[j]);
    }
  }
}

__global__ __launch_bounds__(256) void scan_phase2(const int* __restrict__ blockSums,
                                                   int* __restrict__ blockOffs, int nb,
                                                   int* __restrict__ total_out) {
  __shared__ int sm[256];
  int tid = threadIdx.x;
  int v = (tid < nb) ? blockSums[tid] : 0;
  sm[tid] = v;
  __syncthreads();
#pragma unroll
  for (int o = 1; o < 256; o <<= 1) {
    int t = (tid >= o) ? sm[tid - o] : 0;
    __syncthreads();
    sm[tid] += t;
    __syncthreads();
  }
  if (tid < nb) blockOffs[tid] = sm[tid] - v;  // exclusive
  if (tid == 255) *total_out = sm[255];        // offs[N] = E
}

__global__ __launch_bounds__(256) void scan_phase3(const int* __restrict__ deg,
                                                   const int* __restrict__ blockOffs,
                                                   int* __restrict__ offs, int n) {
  __shared__ int sm[256];
  int tid = threadIdx.x;
  int i = blockIdx.x * 256 + tid;
  int v = (i < n) ? deg[i] : 0;
  sm[tid] = v;
  __syncthreads();
#pragma unroll
  for (int o = 1; o < 256; o <<= 1) {
    int t = (tid >= o) ? sm[tid - o] : 0;
    __syncthreads();
    sm[tid] += t;
    __syncthreads();
  }
  int ex = sm[tid] - v + blockOffs[blockIdx.x];
  if (i < n) offs[i] = ex;
}

__global__ __launch_bounds__(256) void scatter_edges(const int* __restrict__ ei,
                                                     const int* __restrict__ offs,
                                                     const int* __restrict__ rank,
                                                     int* __restrict__ csr_src, int E) {
  int i = blockIdx.x * 256 + threadIdx.x;
  if (i < E) {
    int dst = ei[E + i];
    csr_src[offs[dst] + rank[i]] = ei[i];   // no atomic
  }
}

// ---------------- MFMA bf16 GEMM + alpha + packed bf16 store ----------------
// C[M,256] = A[M,K] @ B[K,256]bf16 (B pre-packed in fragment order).
// A-frag: lane holds A[m = lane&15][k = (lane>>4)*8 + j]
// B-frag: lane holds B[k = (lane>>4)*8 + j][n = lane&15]  (packed Bp)
// D: col = lane&15, row = (lane>>4)*4 + reg   [m89/m91-verified layouts]
template <int KS, bool AF32>  // K = 32*KS
__global__ __launch_bounds__(256) void gemm_mfma(
    const void* __restrict__ Aptr, const u16* __restrict__ Bp,
    const float* __restrict__ a_s, const float* __restrict__ a_d,
    u16* __restrict__ hf16, float* __restrict__ al_s, float* __restrict__ al_d, int M) {
  const int K = 32 * KS;
  int lane = threadIdx.x & 63;
  int wv = threadIdx.x >> 6;
  int q = lane >> 4, r = lane & 15;
  int m0 = blockIdx.x * 64 + wv * 16;

  bf16x8 af[KS];
  if (AF32) {
    int ar = m0 + r; if (ar >= M) ar = M - 1;   // x has exactly M rows; clamp (stores guarded)
    const float* arow = (const float*)Aptr + (size_t)ar * K + q * 8;
#pragma unroll
    for (int ks = 0; ks < KS; ++ks) {
      float4 v0 = *(const float4*)(arow + ks * 32);
      float4 v1 = *(const float4*)(arow + ks * 32 + 4);
      bf16x8 t;
      t[0] = (short)f2bf(v0.x); t[1] = (short)f2bf(v0.y);
      t[2] = (short)f2bf(v0.z); t[3] = (short)f2bf(v0.w);
      t[4] = (short)f2bf(v1.x); t[5] = (short)f2bf(v1.y);
      t[6] = (short)f2bf(v1.z); t[7] = (short)f2bf(v1.w);
      af[ks] = t;
    }
  } else {
    const u16* arow = (const u16*)Aptr + (size_t)(m0 + r) * K + q * 8;  // padded buffer
#pragma unroll
    for (int ks = 0; ks < KS; ++ks) af[ks] = *(const bf16x8*)(arow + ks * 32);
  }

  int node_base = m0 + q * 4;
#pragma unroll
  for (int h = 0; h < NH; ++h) {
    f32x4 acc[4];
#pragma unroll
    for (int c4 = 0; c4 < 4; ++c4) {
      acc[c4] = (f32x4){0.f, 0.f, 0.f, 0.f};
      const u16* bp = Bp + ((size_t)q * 256 + (h * 4 + c4) * 16 + r) * 8;
#pragma unroll
      for (int ks = 0; ks < KS; ++ks) {
        bf16x8 bf = *(const bf16x8*)(bp + (size_t)ks * 4 * 256 * 8);
        acc[c4] = __builtin_amdgcn_mfma_f32_16x16x32_bf16(af[ks], bf, acc[c4], 0, 0, 0);
      }
    }
    // epilogue for this head: alpha partials + packed bf16 stores
    float ps[4] = {0.f, 0.f, 0.f, 0.f}, pd[4] = {0.f, 0.f, 0.f, 0.f};
#pragma unroll
    for (int c4 = 0; c4 < 4; ++c4) {
      float sa = a_s[h * HID + c4 * 16 + r];
      float da = a_d[h * HID + c4 * 16 + r];
#pragma unroll
      for (int reg = 0; reg < 4; ++reg) {
        float v = acc[c4][reg];
        ps[reg] += v * sa;
        pd[reg] += v * da;
        int node = node_base + reg;
        if (node < M) hf16[(size_t)node * NC + (c4 * 16 + r) * NH + h] = f2bf(v);
      }
    }
#pragma unroll
    for (int reg = 0; reg < 4; ++reg) {
#pragma unroll
      for (int o = 1; o < 16; o <<= 1) {
        ps[reg] += __shfl_xor(ps[reg], o);
        pd[reg] += __shfl_xor(pd[reg], o);
      }
      int node = node_base + reg;
      if (r == 0 && node < M) {
        al_s[node * NH + h] = ps[reg];
        al_d[node * NH + h] = pd[reg];
      }
    }
  }
}

// ---------------- aggregation: one wave per destination node ----------------
// 12500 blocks x 4 waves, HW-scheduled (measured best: the HW command
// processor rebalances at block granularity; SW queues (R9) and static
// persistence (R11) both regressed). Mask-padded chunks of 8, depth-1
// pipeline on gathers, denom via shfl tree. No max-shift: logits bounded
// ~|e|<20 => exp(e)/sum identical to reference's shifted softmax.
template <bool FINAL>
__global__ __launch_bounds__(256) void agg_kernel(const u16* __restrict__ hf16,
                                                  const float4* __restrict__ al_s4,
                                                  const float4* __restrict__ al_d4,
                                                  const int* __restrict__ offs, const int* __restrict__ csr_src,
                                                  const float* __restrict__ bias, void* __restrict__ out_v, int n) {
  int lane = threadIdx.x & 63;
  int node = blockIdx.x * 4 + (threadIdx.x >> 6);
  if (node >= n) return;
  float4 ad = al_d4[node];
  int lj = lane & 7;           // edge slot within chunk (weight lanes)
  int hsel = (lane >> 3) & 3;  // head handled by this lane in the weight phase
  float adv = hsel == 0 ? ad.x : (hsel == 1 ? ad.y : (hsel == 2 ? ad.z : ad.w));
  float c0 = 0.f, c1 = 0.f, c2 = 0.f, c3 = 0.f;
  float dacc = 0.f;            // per-head denom partial on lanes 0,8,16,24
  int s = offs[node], e = offs[node + 1];
  int nch = (e - s + 7) >> 3;
  int i = s;

  int vidx = 0;
  float4 as = make_float4(0.f, 0.f, 0.f, 0.f);
  ushort4 hv[8];
  if (nch > 0) {
    int id0 = i + lj; if (id0 >= e) id0 = e - 1;   // clamp: masked by w=0 later
    vidx = csr_src[id0];
    as = al_s4[vidx];
#pragma unroll
    for (int j = 0; j < 8; ++j) {
      int sa = __builtin_amdgcn_readlane(vidx, j);
      hv[j] = ((const ushort4*)(hf16 + (size_t)sa * NC))[lane];
    }
  }

  for (int ch = 0; ch < nch; ++ch) {
    bool last = (ch + 1 == nch);
    // ---- weight phase (lanes 0..31 meaningful) ----
    float asv = hsel == 0 ? as.x : (hsel == 1 ? as.y : (hsel == 2 ? as.z : as.w));
    float ev = asv + adv;
    ev = ev >= 0.f ? ev : NEG * ev;
    float wv = __expf(ev);
    if (i + lj >= e) wv = 0.f;                     // mask padded slots
    float t = wv;
    t += __shfl_xor(t, 1); t += __shfl_xor(t, 2); t += __shfl_xor(t, 4);
    dacc += t;                                     // lanes 0,8,16,24 hold head sums
    // ---- prefetch next chunk ----
    int vidx_n = 0;
    float4 as_n = make_float4(0.f, 0.f, 0.f, 0.f);
    ushort4 hn[8];
    if (!last) {
      int id1 = i + 8 + lj; if (id1 >= e) id1 = e - 1;
      vidx_n = csr_src[id1];
      as_n = al_s4[vidx_n];
#pragma unroll
      for (int j = 0; j < 8; ++j) {
        int sa = __builtin_amdgcn_readlane(vidx_n, j);
        hn[j] = ((const ushort4*)(hf16 + (size_t)sa * NC))[lane];
      }
    }
    // ---- accumulate current chunk ----
#pragma unroll
    for (int j = 0; j < 8; ++j) {
      float wx = readlane_f(wv, j);
      float wy = readlane_f(wv, 8 + j);
      float wz = readlane_f(wv, 16 + j);
      float ww = readlane_f(wv, 24 + j);
      c0 += wx * bf2f(hv[j].x);
      c1 += wy * bf2f(hv[j].y);
      c2 += wz * bf2f(hv[j].z);
      c3 += ww * bf2f(hv[j].w);
    }
    if (!last) {
      vidx = vidx_n; as = as_n;
#pragma unroll
      for (int j = 0; j < 8; ++j) hv[j] = hn[j];
    }
    i += 8;
  }
  float d0 = readlane_f(dacc, 0), d1 = readlane_f(dacc, 8);
  float d2 = readlane_f(dacc, 16), d3 = readlane_f(dacc, 24);
  float val = 0.25f * (c0 / (d0 + 1e-16f) + c1 / (d1 + 1e-16f) +
                       c2 / (d2 + 1e-16f) + c3 / (d3 + 1e-16f)) + bias[lane];
  if (!FINAL) {
    // layer-1 output: relu + bf16 (feeds layer-2 MFMA GEMM directly)
    ((u16*)out_v)[(size_t)node * HID + lane] = f2bf(fmaxf(val, 0.f));
  } else {
    float mx = val;
#pragma unroll
    for (int o = 32; o >= 1; o >>= 1) mx = fmaxf(mx, __shfl_xor(mx, o));
    float ex = __expf(val - mx);
    float sm = ex;
#pragma unroll
    for (int o = 32; o >= 1; o >>= 1) sm += __shfl_xor(sm, o);
    ((float*)out_v)[(size_t)node * HID + lane] = (val - mx) - logf(sm);
  }
}

// ---------------- launch ----------------
extern "C" void kernel_launch(void* const* d_in, const int* in_sizes, int n_in,
                              void* d_out, int out_size, void* d_ws, size_t ws_size,
                              hipStream_t stream) {
  const float* x   = (const float*)d_in[0];
  const int*   ei  = (const int*)d_in[1];   // int32 (JAX x64 disabled canonicalizes int64)
  const float* W1  = (const float*)d_in[2];
  const float* as1 = (const float*)d_in[3];
  const float* ad1 = (const float*)d_in[4];
  const float* b1  = (const float*)d_in[5];
  const float* W2  = (const float*)d_in[6];
  const float* as2 = (const float*)d_in[7];
  const float* ad2 = (const float*)d_in[8];
  const float* b2  = (const float*)d_in[9];
  float* out = (float*)d_out;

  const int N = NNODE;
  const int E = in_sizes[1] / 2;

  char* base = (char*)d_ws;
  size_t off = 0;
  auto alloc = [&](size_t bytes) -> void* {
    void* p = base + off;
    off += (bytes + 255) & ~(size_t)255;
    return p;
  };
  u16*    hf16   = (u16*)alloc((size_t)N * NC * 2);       // 25.6 MB packed [node][c][h]
  u16*    h1bf   = (u16*)alloc((size_t)MPAD * HID * 2);   // 6.4 MB bf16 layer-1 out (padded)
  u16*    Bp1    = (u16*)alloc((size_t)FIN * NC * 2);     // packed W1
  u16*    Bp2    = (u16*)alloc((size_t)HID * NC * 2);     // packed W2
  float*  al_s   = (float*)alloc((size_t)N * NH * 4);
  float*  al_d   = (float*)alloc((size_t)N * NH * 4);
  int*    deg    = (int*)alloc((size_t)N * 4);
  int*    offs   = (int*)alloc((size_t)(N + 1) * 4);
  int*    rank   = (int*)alloc((size_t)E * 4);
  int*    csr    = (int*)alloc((size_t)E * 4);
  int*    bsums  = (int*)alloc(256 * 4);
  int*    boffs  = (int*)alloc(256 * 4);

  const int edgeBlocks = (E + 255) / 256;       // 3125
  const int gemmBlocks = MPAD / 64;             // 782
  const int nodeBlocks = (N + 3) / 4;           // 12500: 4 waves/block, HW-balanced
  const int packBlocks = (FIN * NC + HID * NC + 255) / 256;  // 192

  // --- CSR build + weight pack (shared by both layers) ---
  hipMemsetAsync(deg, 0, (size_t)N * 4, stream);
  count_deg<<<edgeBlocks, 256, 0, stream>>>(ei, deg, rank, E);
  scan1_pack<<<SCANB + packBlocks, 256, 0, stream>>>(deg, bsums, N, W1, W2, Bp1, Bp2);
  scan_phase2<<<1, 256, 0, stream>>>(bsums, boffs, SCANB, offs + N);
  scan_phase3<<<SCANB, 256, 0, stream>>>(deg, boffs, offs, N);
  scatter_edges<<<edgeBlocks, 256, 0, stream>>>(ei, offs, rank, csr, E);

  // --- layer 1 (A = x fp32, converted in-register) ---
  gemm_mfma<4, true><<<gemmBlocks, 256, 0, stream>>>(x, Bp1, as1, ad1, hf16, al_s, al_d, N);
  agg_kernel<false><<<nodeBlocks, 256, 0, stream>>>(hf16, (const float4*)al_s, (const float4*)al_d,
                                                    offs, csr, b1, h1bf, N);

  // --- layer 2 (A = h1bf bf16) ---
  gemm_mfma<2, false><<<gemmBlocks, 256, 0, stream>>>(h1bf, Bp2, as2, ad2, hf16, al_s, al_d, N);
  agg_kernel<true><<<nodeBlocks, 256, 0, stream>>>(hf16, (const float4*)al_s, (const float4*)al_d,
                                                   offs, csr, b2, out, N);
}

// Round 13
// 312.681 us; speedup vs baseline: 2.4379x; 1.0241x over previous
//
#include <hip/hip_runtime.h>
#include <math.h>

// Problem constants (GATModel: N=50000, E=800000, F_IN=128, HID=OUT=64, H=4)
constexpr int NNODE = 50000;
constexpr int FIN   = 128;
constexpr int HID   = 64;
constexpr int NH    = 4;
constexpr int NC    = 256;   // NH * HID
constexpr float NEG = 0.2f;
constexpr int MPAD  = 50048; // NNODE padded to 64-row tiles (782*64)
constexpr int SCANB = (NNODE + 255) / 256;  // 196

typedef unsigned short u16;
typedef short bf16x8 __attribute__((ext_vector_type(8)));
typedef float f32x4 __attribute__((ext_vector_type(4)));

__device__ __forceinline__ u16 f2bf(float f) {  // round-to-nearest-even
  unsigned int u = __float_as_uint(f);
  return (u16)((u + 0x7FFF + ((u >> 16) & 1)) >> 16);
}
__device__ __forceinline__ float bf2f(u16 h) {
  return __uint_as_float(((unsigned int)h) << 16);
}
__device__ __forceinline__ float readlane_f(float v, int l) {
  return __int_as_float(__builtin_amdgcn_readlane(__float_as_int(v), l));
}

// ---------------- fused: count_deg + weight packing (independent work) ----------------
// Blocks [0,edgeBlocks): rank[i] = atomicAdd(&deg[dst],1)  (rank reused by scatter).
// Blocks [edgeBlocks,+192): pack W1/W2 fp32 -> bf16 MFMA B-fragment order.
__global__ __launch_bounds__(256) void count_pack(const int* __restrict__ ei, int* __restrict__ deg,
                                                  int* __restrict__ rank, int E, int edgeBlocks,
                                                  const float* __restrict__ W1, const float* __restrict__ W2,
                                                  u16* __restrict__ Bp1, u16* __restrict__ Bp2) {
  int b = blockIdx.x;
  if (b < edgeBlocks) {
    int i = b * 256 + threadIdx.x;
    if (i < E) rank[i] = atomicAdd(&deg[ei[E + i]], 1);
  } else {
    int i = (b - edgeBlocks) * 256 + threadIdx.x;
    const int t1 = FIN * NC;
    const int t2 = HID * NC;
    if (i < t1) {
      int k = i >> 8, c = i & 255;
      Bp1[((size_t)(k >> 3) * 256 + c) * 8 + (k & 7)] = f2bf(W1[i]);
    } else if (i < t1 + t2) {
      int j = i - t1;
      int k = j >> 8, c = j & 255;
      Bp2[((size_t)(k >> 3) * 256 + c) * 8 + (k & 7)] = f2bf(W2[j]);
    }
  }
}

// ---------------- scan phase 1: per-block degree sums ----------------
__global__ __launch_bounds__(256) void scan_phase1(const int* __restrict__ deg,
                                                   int* __restrict__ blockSums, int n) {
  __shared__ int sm[256];
  int tid = threadIdx.x;
  int i = blockIdx.x * 256 + tid;
  sm[tid] = (i < n) ? deg[i] : 0;
  __syncthreads();
#pragma unroll
  for (int o = 128; o > 0; o >>= 1) {
    if (tid < o) sm[tid] += sm[tid + o];
    __syncthreads();
  }
  if (tid == 0) blockSums[blockIdx.x] = sm[0];
}

// ---------------- scan phases 2+3 fused ----------------
// Each block redundantly scans the 196 block sums in LDS (trivial work),
// picks its own offset, then does the per-element exclusive scan.
__global__ __launch_bounds__(256) void scan_phase23(const int* __restrict__ blockSums,
                                                    const int* __restrict__ deg,
                                                    int* __restrict__ offs, int n) {
  __shared__ int ss[256];
  __shared__ int sm[256];
  int tid = threadIdx.x;
  ss[tid] = (tid < SCANB) ? blockSums[tid] : 0;
  __syncthreads();
#pragma unroll
  for (int o = 1; o < 256; o <<= 1) {
    int t = (tid >= o) ? ss[tid - o] : 0;
    __syncthreads();
    ss[tid] += t;
    __syncthreads();
  }
  int blockOff = (blockIdx.x == 0) ? 0 : ss[blockIdx.x - 1];
  int i = blockIdx.x * 256 + tid;
  int v = (i < n) ? deg[i] : 0;
  sm[tid] = v;
  __syncthreads();
#pragma unroll
  for (int o = 1; o < 256; o <<= 1) {
    int t = (tid >= o) ? sm[tid - o] : 0;
    __syncthreads();
    sm[tid] += t;
    __syncthreads();
  }
  int ex = sm[tid] - v + blockOff;
  if (i < n) offs[i] = ex;
  if (blockIdx.x == SCANB - 1 && tid == 255) offs[n] = ss[SCANB - 1];  // offs[N] = E
}

// ---------------- MFMA bf16 GEMM body (device fn, called from fused kernels) ----------------
// C[M,256] = A[M,K] @ B[K,256]bf16 (B pre-packed in fragment order).
// A-frag: lane holds A[m = lane&15][k = (lane>>4)*8 + j]
// B-frag: lane holds B[k = (lane>>4)*8 + j][n = lane&15]  (packed Bp)
// D: col = lane&15, row = (lane>>4)*4 + reg   [m89/m91-verified layouts]
template <int KS, bool AF32>  // K = 32*KS
__device__ __forceinline__ void gemm_body(
    int bx, const void* __restrict__ Aptr, const u16* __restrict__ Bp,
    const float* __restrict__ a_s, const float* __restrict__ a_d,
    u16* __restrict__ hf16, float* __restrict__ al_s, float* __restrict__ al_d, int M) {
  const int K = 32 * KS;
  int lane = threadIdx.x & 63;
  int wv = threadIdx.x >> 6;
  int q = lane >> 4, r = lane & 15;
  int m0 = bx * 64 + wv * 16;

  bf16x8 af[KS];
  if (AF32) {
    int ar = m0 + r; if (ar >= M) ar = M - 1;   // x has exactly M rows; clamp (stores guarded)
    const float* arow = (const float*)Aptr + (size_t)ar * K + q * 8;
#pragma unroll
    for (int ks = 0; ks < KS; ++ks) {
      float4 v0 = *(const float4*)(arow + ks * 32);
      float4 v1 = *(const float4*)(arow + ks * 32 + 4);
      bf16x8 t;
      t[0] = (short)f2bf(v0.x); t[1] = (short)f2bf(v0.y);
      t[2] = (short)f2bf(v0.z); t[3] = (short)f2bf(v0.w);
      t[4] = (short)f2bf(v1.x); t[5] = (short)f2bf(v1.y);
      t[6] = (short)f2bf(v1.z); t[7] = (short)f2bf(v1.w);
      af[ks] = t;
    }
  } else {
    const u16* arow = (const u16*)Aptr + (size_t)(m0 + r) * K + q * 8;  // padded buffer
#pragma unroll
    for (int ks = 0; ks < KS; ++ks) af[ks] = *(const bf16x8*)(arow + ks * 32);
  }

  int node_base = m0 + q * 4;
#pragma unroll
  for (int h = 0; h < NH; ++h) {
    f32x4 acc[4];
#pragma unroll
    for (int c4 = 0; c4 < 4; ++c4) {
      acc[c4] = (f32x4){0.f, 0.f, 0.f, 0.f};
      const u16* bp = Bp + ((size_t)q * 256 + (h * 4 + c4) * 16 + r) * 8;
#pragma unroll
      for (int ks = 0; ks < KS; ++ks) {
        bf16x8 bf = *(const bf16x8*)(bp + (size_t)ks * 4 * 256 * 8);
        acc[c4] = __builtin_amdgcn_mfma_f32_16x16x32_bf16(af[ks], bf, acc[c4], 0, 0, 0);
      }
    }
    // epilogue for this head: alpha partials + packed bf16 stores
    float ps[4] = {0.f, 0.f, 0.f, 0.f}, pd[4] = {0.f, 0.f, 0.f, 0.f};
#pragma unroll
    for (int c4 = 0; c4 < 4; ++c4) {
      float sa = a_s[h * HID + c4 * 16 + r];
      float da = a_d[h * HID + c4 * 16 + r];
#pragma unroll
      for (int reg = 0; reg < 4; ++reg) {
        float v = acc[c4][reg];
        ps[reg] += v * sa;
        pd[reg] += v * da;
        int node = node_base + reg;
        if (node < M) hf16[(size_t)node * NC + (c4 * 16 + r) * NH + h] = f2bf(v);
      }
    }
#pragma unroll
    for (int reg = 0; reg < 4; ++reg) {
#pragma unroll
      for (int o = 1; o < 16; o <<= 1) {
        ps[reg] += __shfl_xor(ps[reg], o);
        pd[reg] += __shfl_xor(pd[reg], o);
      }
      int node = node_base + reg;
      if (r == 0 && node < M) {
        al_s[node * NH + h] = ps[reg];
        al_d[node * NH + h] = pd[reg];
      }
    }
  }
}

// ---------------- fused: gemm layer-1 + atomic-free edge scatter ----------------
// Independent work in one launch so the MFMA-bound gemm overlaps the
// memory-bound scatter. Gemm blocks FIRST (dispatch order) so compute starts
// immediately and scatter fills the memory pipes around it.
__global__ __launch_bounds__(256) void gemm1_scatter(
    const float* __restrict__ x, const u16* __restrict__ Bp1,
    const float* __restrict__ a_s, const float* __restrict__ a_d,
    u16* __restrict__ hf16, float* __restrict__ al_s, float* __restrict__ al_d, int M,
    const int* __restrict__ ei, const int* __restrict__ offs, const int* __restrict__ rank,
    int* __restrict__ csr_src, int E, int gemmBlocks) {
  int b = blockIdx.x;
  if (b < gemmBlocks) {
    gemm_body<4, true>(b, x, Bp1, a_s, a_d, hf16, al_s, al_d, M);
  } else {
    int i = (b - gemmBlocks) * 256 + threadIdx.x;
    if (i < E) {
      int dst = ei[E + i];
      csr_src[offs[dst] + rank[i]] = ei[i];   // no atomic (rank from count_pack)
    }
  }
}

__global__ __launch_bounds__(256) void gemm2_kernel(
    const u16* __restrict__ h1bf, const u16* __restrict__ Bp2,
    const float* __restrict__ a_s, const float* __restrict__ a_d,
    u16* __restrict__ hf16, float* __restrict__ al_s, float* __restrict__ al_d, int M) {
  gemm_body<2, false>(blockIdx.x, h1bf, Bp2, a_s, a_d, hf16, al_s, al_d, M);
}

// ---------------- aggregation: one wave per destination node ----------------
// 12500 blocks x 4 waves, HW-scheduled (measured best: the HW command
// processor rebalances at block granularity; SW queues (R9) and static
// persistence (R11) both regressed). Mask-padded chunks of 8, depth-1
// pipeline on gathers, denom via shfl tree. No max-shift: logits bounded
// ~|e|<20 => exp(e)/sum identical to reference's shifted softmax.
template <bool FINAL>
__global__ __launch_bounds__(256) void agg_kernel(const u16* __restrict__ hf16,
                                                  const float4* __restrict__ al_s4,
                                                  const float4* __restrict__ al_d4,
                                                  const int* __restrict__ offs, const int* __restrict__ csr_src,
                                                  const float* __restrict__ bias, void* __restrict__ out_v, int n) {
  int lane = threadIdx.x & 63;
  int node = blockIdx.x * 4 + (threadIdx.x >> 6);
  if (node >= n) return;
  float4 ad = al_d4[node];
  int lj = lane & 7;           // edge slot within chunk (weight lanes)
  int hsel = (lane >> 3) & 3;  // head handled by this lane in the weight phase
  float adv = hsel == 0 ? ad.x : (hsel == 1 ? ad.y : (hsel == 2 ? ad.z : ad.w));
  float c0 = 0.f, c1 = 0.f, c2 = 0.f, c3 = 0.f;
  float dacc = 0.f;            // per-head denom partial on lanes 0,8,16,24
  int s = offs[node], e = offs[node + 1];
  int nch = (e - s + 7) >> 3;
  int i = s;

  int vidx = 0;
  float4 as = make_float4(0.f, 0.f, 0.f, 0.f);
  ushort4 hv[8];
  if (nch > 0) {
    int id0 = i + lj; if (id0 >= e) id0 = e - 1;   // clamp: masked by w=0 later
    vidx = csr_src[id0];
    as = al_s4[vidx];
#pragma unroll
    for (int j = 0; j < 8; ++j) {
      int sa = __builtin_amdgcn_readlane(vidx, j);
      hv[j] = ((const ushort4*)(hf16 + (size_t)sa * NC))[lane];
    }
  }

  for (int ch = 0; ch < nch; ++ch) {
    bool last = (ch + 1 == nch);
    // ---- weight phase (lanes 0..31 meaningful) ----
    float asv = hsel == 0 ? as.x : (hsel == 1 ? as.y : (hsel == 2 ? as.z : as.w));
    float ev = asv + adv;
    ev = ev >= 0.f ? ev : NEG * ev;
    float wv = __expf(ev);
    if (i + lj >= e) wv = 0.f;                     // mask padded slots
    float t = wv;
    t += __shfl_xor(t, 1); t += __shfl_xor(t, 2); t += __shfl_xor(t, 4);
    dacc += t;                                     // lanes 0,8,16,24 hold head sums
    // ---- prefetch next chunk ----
    int vidx_n = 0;
    float4 as_n = make_float4(0.f, 0.f, 0.f, 0.f);
    ushort4 hn[8];
    if (!last) {
      int id1 = i + 8 + lj; if (id1 >= e) id1 = e - 1;
      vidx_n = csr_src[id1];
      as_n = al_s4[vidx_n];
#pragma unroll
      for (int j = 0; j < 8; ++j) {
        int sa = __builtin_amdgcn_readlane(vidx_n, j);
        hn[j] = ((const ushort4*)(hf16 + (size_t)sa * NC))[lane];
      }
    }
    // ---- accumulate current chunk ----
#pragma unroll
    for (int j = 0; j < 8; ++j) {
      float wx = readlane_f(wv, j);
      float wy = readlane_f(wv, 8 + j);
      float wz = readlane_f(wv, 16 + j);
      float ww = readlane_f(wv, 24 + j);
      c0 += wx * bf2f(hv[j].x);
      c1 += wy * bf2f(hv[j].y);
      c2 += wz * bf2f(hv[j].z);
      c3 += ww * bf2f(hv[j].w);
    }
    if (!last) {
      vidx = vidx_n; as = as_n;
#pragma unroll
      for (int j = 0; j < 8; ++j) hv[j] = hn[j];
    }
    i += 8;
  }
  float d0 = readlane_f(dacc, 0), d1 = readlane_f(dacc, 8);
  float d2 = readlane_f(dacc, 16), d3 = readlane_f(dacc, 24);
  float val = 0.25f * (c0 / (d0 + 1e-16f) + c1 / (d1 + 1e-16f) +
                       c2 / (d2 + 1e-16f) + c3 / (d3 + 1e-16f)) + bias[lane];
  if (!FINAL) {
    // layer-1 output: relu + bf16 (feeds layer-2 MFMA GEMM directly)
    ((u16*)out_v)[(size_t)node * HID + lane] = f2bf(fmaxf(val, 0.f));
  } else {
    float mx = val;
#pragma unroll
    for (int o = 32; o >= 1; o >>= 1) mx = fmaxf(mx, __shfl_xor(mx, o));
    float ex = __expf(val - mx);
    float sm = ex;
#pragma unroll
    for (int o = 32; o >= 1; o >>= 1) sm += __shfl_xor(sm, o);
    ((float*)out_v)[(size_t)node * HID + lane] = (val - mx) - logf(sm);
  }
}

// ---------------- launch ----------------
extern "C" void kernel_launch(void* const* d_in, const int* in_sizes, int n_in,
                              void* d_out, int out_size, void* d_ws, size_t ws_size,
                              hipStream_t stream) {
  const float* x   = (const float*)d_in[0];
  const int*   ei  = (const int*)d_in[1];   // int32 (JAX x64 disabled canonicalizes int64)
  const float* W1  = (const float*)d_in[2];
  const float* as1 = (const float*)d_in[3];
  const float* ad1 = (const float*)d_in[4];
  const float* b1  = (const float*)d_in[5];
  const float* W2  = (const float*)d_in[6];
  const float* as2 = (const float*)d_in[7];
  const float* ad2 = (const float*)d_in[8];
  const float* b2  = (const float*)d_in[9];
  float* out = (float*)d_out;

  const int N = NNODE;
  const int E = in_sizes[1] / 2;

  char* base = (char*)d_ws;
  size_t off = 0;
  auto alloc = [&](size_t bytes) -> void* {
    void* p = base + off;
    off += (bytes + 255) & ~(size_t)255;
    return p;
  };
  u16*    hf16   = (u16*)alloc((size_t)N * NC * 2);       // 25.6 MB packed [node][c][h]
  u16*    h1bf   = (u16*)alloc((size_t)MPAD * HID * 2);   // 6.4 MB bf16 layer-1 out (padded)
  u16*    Bp1    = (u16*)alloc((size_t)FIN * NC * 2);     // packed W1
  u16*    Bp2    = (u16*)alloc((size_t)HID * NC * 2);     // packed W2
  float*  al_s   = (float*)alloc((size_t)N * NH * 4);
  float*  al_d   = (float*)alloc((size_t)N * NH * 4);
  int*    deg    = (int*)alloc((size_t)N * 4);
  int*    offs   = (int*)alloc((size_t)(N + 1) * 4);
  int*    rank   = (int*)alloc((size_t)E * 4);
  int*    csr    = (int*)alloc((size_t)E * 4);
  int*    bsums  = (int*)alloc(256 * 4);

  const int edgeBlocks = (E + 255) / 256;       // 3125
  const int gemmBlocks = MPAD / 64;             // 782
  const int nodeBlocks = (N + 3) / 4;           // 12500: 4 waves/block, HW-balanced
  const int packBlocks = (FIN * NC + HID * NC + 255) / 256;  // 192

  // --- CSR build + weight pack (fused where independent) ---
  hipMemsetAsync(deg, 0, (size_t)N * 4, stream);
  count_pack<<<edgeBlocks + packBlocks, 256, 0, stream>>>(ei, deg, rank, E, edgeBlocks, W1, W2, Bp1, Bp2);
  scan_phase1<<<SCANB, 256, 0, stream>>>(deg, bsums, N);
  scan_phase23<<<SCANB, 256, 0, stream>>>(bsums, deg, offs, N);

  // --- layer 1 GEMM (MFMA) overlapped with edge scatter (independent) ---
  gemm1_scatter<<<gemmBlocks + edgeBlocks, 256, 0, stream>>>(
      x, Bp1, as1, ad1, hf16, al_s, al_d, N,
      ei, offs, rank, csr, E, gemmBlocks);
  agg_kernel<false><<<nodeBlocks, 256, 0, stream>>>(hf16, (const float4*)al_s, (const float4*)al_d,
                                                    offs, csr, b1, h1bf, N);

  // --- layer 2 ---
  gemm2_kernel<<<gemmBlocks, 256, 0, stream>>>(h1bf, Bp2, as2, ad2, hf16, al_s, al_d, N);
  agg_kernel<true><<<nodeBlocks, 256, 0, stream>>>(hf16, (const float4*)al_s, (const float4*)al_d,
                                                   offs, csr, b2, out, N);
}